// Round 4
// baseline (94.131 us; speedup 1.0000x reference)
//
#include <hip/hip_runtime.h>

// LIF spike recurrence:
//   u_t = u_{t-1} - Vth * o_{t-1} + x_t ;  o_t = (u_t > Vth) ? 1 : 0
// x: [T=16, N=4194304] float32, out: same shape float32.
//
// Each thread owns 4 consecutive floats (native float4 vector). Phase 1
// issues ALL 16 time-plane loads; a sched_barrier(0) pins them before any
// compute so 16 global_load_dwordx4 stay in flight (deep MLP to cover ~900cy
// HBM latency; round-3 showed the compiler otherwise re-sinks them, VGPR=32).
// Phase 2 runs the recurrence and writes outputs with nontemporal stores
// (keeps x L3-resident; WRITE_SIZE is exactly compulsory 268 MB).

#define LIF_VTH   1.0f
#define LIF_STEPS 16

typedef float fx4 __attribute__((ext_vector_type(4)));

__global__ __launch_bounds__(256) void LIFSpike_84542136254876_kernel(
    const fx4* __restrict__ x, fx4* __restrict__ out, int n4) {
    int i = blockIdx.x * blockDim.x + threadIdx.x;
    if (i >= n4) return;

    // Phase 1: issue all 16 loads.
    fx4 xt[LIF_STEPS];
#pragma unroll
    for (int t = 0; t < LIF_STEPS; ++t) {
        xt[t] = x[(size_t)t * (size_t)n4 + (size_t)i];
    }
    // No instruction may cross this point: all 16 loads are issued before
    // any compute, forcing the register allocator to keep them in flight.
    __builtin_amdgcn_sched_barrier(0);

    // Phase 2: recurrence + stores.
    fx4 u = (fx4)0.0f;
    fx4 o = (fx4)0.0f;
#pragma unroll
    for (int t = 0; t < LIF_STEPS; ++t) {
        u = u - o + xt[t];
        fx4 on;
        on.x = (u.x > LIF_VTH) ? 1.0f : 0.0f;
        on.y = (u.y > LIF_VTH) ? 1.0f : 0.0f;
        on.z = (u.z > LIF_VTH) ? 1.0f : 0.0f;
        on.w = (u.w > LIF_VTH) ? 1.0f : 0.0f;
        o = on;
        __builtin_nontemporal_store(o, &out[(size_t)t * (size_t)n4 + (size_t)i]);
    }
}

extern "C" void kernel_launch(void* const* d_in, const int* in_sizes, int n_in,
                              void* d_out, int out_size, void* d_ws, size_t ws_size,
                              hipStream_t stream) {
    const float* x = (const float*)d_in[0];
    float* out = (float*)d_out;

    int total = in_sizes[0];          // T * N
    int n = total / LIF_STEPS;        // spatial elements per timestep
    int n4 = n / 4;                   // float4 elements per timestep

    int block = 256;
    int grid = (n4 + block - 1) / block;

    LIFSpike_84542136254876_kernel<<<grid, block, 0, stream>>>(
        (const fx4*)x, (fx4*)out, n4);
}

// Round 5
// 89.040 us; speedup vs baseline: 1.0572x; 1.0572x over previous
//
#include <hip/hip_runtime.h>

// LIF spike recurrence:
//   u_t = u_{t-1} - Vth * o_{t-1} + x_t ;  o_t = (u_t > Vth) ? 1 : 0
// x: [T=16, N=4194304] float32, out: same shape float32.
//
// Each thread owns 4 consecutive floats (native float4 vector). Phase 1
// issues ALL 16 time-plane loads; an empty asm volatile consuming all 16
// values forces them simultaneously live (the compiler cannot re-sink the
// loads — rounds 3/4 showed both plain unroll and sched_barrier(0) get
// undone by pre-RA scheduling, VGPR stuck at 32-36). Phase 2 runs the
// recurrence and writes outputs with nontemporal stores (keeps x
// L3-resident; WRITE_SIZE is exactly the compulsory 268 MB).

#define LIF_VTH   1.0f
#define LIF_STEPS 16

typedef float fx4 __attribute__((ext_vector_type(4)));

__global__ __launch_bounds__(256) void LIFSpike_84542136254876_kernel(
    const fx4* __restrict__ x, fx4* __restrict__ out, int n4) {
    int i = blockIdx.x * blockDim.x + threadIdx.x;
    if (i >= n4) return;

    // Phase 1: issue all 16 loads.
    fx4 xt[LIF_STEPS];
#pragma unroll
    for (int t = 0; t < LIF_STEPS; ++t) {
        xt[t] = x[(size_t)t * (size_t)n4 + (size_t)i];
    }
    // Force all 16 load results live at this point: the register allocator
    // must keep 64 VGPRs of in-flight data, so all 16 global_load_dwordx4
    // are issued back-to-back (deep MLP). Compiler still inserts correct
    // vmcnt waits since these are ordinary loads.
    asm volatile("" ::
        "v"(xt[0]),  "v"(xt[1]),  "v"(xt[2]),  "v"(xt[3]),
        "v"(xt[4]),  "v"(xt[5]),  "v"(xt[6]),  "v"(xt[7]),
        "v"(xt[8]),  "v"(xt[9]),  "v"(xt[10]), "v"(xt[11]),
        "v"(xt[12]), "v"(xt[13]), "v"(xt[14]), "v"(xt[15]));

    // Phase 2: recurrence + stores.
    fx4 u = (fx4)0.0f;
    fx4 o = (fx4)0.0f;
#pragma unroll
    for (int t = 0; t < LIF_STEPS; ++t) {
        u = u - o + xt[t];
        fx4 on;
        on.x = (u.x > LIF_VTH) ? 1.0f : 0.0f;
        on.y = (u.y > LIF_VTH) ? 1.0f : 0.0f;
        on.z = (u.z > LIF_VTH) ? 1.0f : 0.0f;
        on.w = (u.w > LIF_VTH) ? 1.0f : 0.0f;
        o = on;
        __builtin_nontemporal_store(o, &out[(size_t)t * (size_t)n4 + (size_t)i]);
    }
}

extern "C" void kernel_launch(void* const* d_in, const int* in_sizes, int n_in,
                              void* d_out, int out_size, void* d_ws, size_t ws_size,
                              hipStream_t stream) {
    const float* x = (const float*)d_in[0];
    float* out = (float*)d_out;

    int total = in_sizes[0];          // T * N
    int n = total / LIF_STEPS;        // spatial elements per timestep
    int n4 = n / 4;                   // float4 elements per timestep

    int block = 256;
    int grid = (n4 + block - 1) / block;

    LIFSpike_84542136254876_kernel<<<grid, block, 0, stream>>>(
        (const fx4*)x, (fx4*)out, n4);
}